// Round 18
// baseline (1593.288 us; speedup 1.0000x reference)
//
#include <hip/hip_runtime.h>
#include <math.h>

#define Bb 8
#define Nn 2048
#define Ee 4096
#define Dd 256
#define HOPS 3

typedef __attribute__((ext_vector_type(4))) float f32x4;
typedef _Float16 f16;
typedef __attribute__((ext_vector_type(8))) _Float16 f16x8;
typedef __attribute__((ext_vector_type(4))) _Float16 f16x4;
typedef __attribute__((ext_vector_type(8))) short s16x8;
typedef __attribute__((ext_vector_type(4))) short s16x4;

__device__ __forceinline__ short f2bf(float f){
  union{float f; unsigned u;} x; x.f=f;
  unsigned r = (x.u + 0x7fffu + ((x.u>>16)&1u)) >> 16;
  return (short)r;
}
__device__ __forceinline__ float bf2f(short h){
  union{unsigned u; float f;} x; x.u = ((unsigned)(unsigned short)h) << 16; return x.f;
}
// XOR-swizzle on 16B granules within a row-major [R][64] 16-bit LDS tile (T2)
__device__ __forceinline__ int swz(int row, int idx){ return idx ^ ((row & 7) << 3); }

enum { HN=0, HT=1 };                                  // hgemm A modes
enum { OF=0, OH=1, OHT=2 };                           // output: f32 / f16 / f16-transposed
enum { EP_NONE=0, EP_BIAS, EP_ADDRELUH, EP_AGG };     // hgemm epilogues (ADDRELUH: f16 aux)
enum { GM_Z=0, GM_UR, GM_M };                         // ggemm A modes
enum { SE_GATE=0, SE_SIG, SE_TANH, SE_GRU };          // ggemm epilogues

// T1: bijective XCD-aware blockIdx remap (all grids have nwg % 8 == 0)
__device__ __forceinline__ void xcd_remap(int& bx, int& by, int& bz) {
  const int nx = gridDim.x, ny = gridDim.y;
  const int nwg = nx * ny * gridDim.z;
  const int lin0 = blockIdx.x + nx * (blockIdx.y + ny * blockIdx.z);
  const int cpx = nwg >> 3;
  const int lin = (lin0 & 7) * cpx + (lin0 >> 3);
  bx = lin % nx;
  const int t1 = lin / nx;
  by = t1 % ny;
  bz = t1 / ny;
}

// -------------- fp16 MFMA GEMM: tile 128x128, BK=64, 8 waves (4x2), 512 thr --------------
// 16x16x32 MFMA (0 bank conflicts). Reg-staged 2-phase. C map: col=lane&15, row=(lane>>4)*4+t.
// Cs (optional, EP_AGG/OF): also emit split-bf16 planes of C (hi at Cs, lo at Cs+csLo).
template<int AMODE, bool AH, int SPL, int EPI, int OUTM>
__global__ __launch_bounds__(512) void hgemm(
    const void* __restrict__ Av, const f16* __restrict__ Bh, void* __restrict__ Cv,
    const float* __restrict__ aux1, const float* __restrict__ aux2,
    const float* __restrict__ bias,
    int M, int Nd, int K, int lda, int ldb, int ldc,
    long sA, long sB, long sC, long sAux1, long sAux2,
    long aLo, long bLo, int maskB, int mask1,
    short* __restrict__ Cs, long csLo)
{
  int bxi, byi, bz;
  xcd_remap(bxi, byi, bz);
  const char* Ab = (const char*)Av + (AH ? bz * sA * 2 : bz * sA * 4);
  Bh += (long)(bz & maskB) * sB;
  char* Cb = (char*)Cv + ((OUTM == OF) ? bz * sC * 4 : bz * sC * 2);
  if (Cs) Cs += (long)bz * sC;
  if (aux1) aux1 += (long)(bz & mask1) * sAux1;   // for EP_ADDRELUH: sAux1 in f32 units (= f16 elems / 2)
  if (aux2) aux2 += bz * sAux2;
  const int m0 = byi * 128;
  const int n0 = bxi * 128;

  constexpr int HLA = 128 * 64;
  constexpr int HLB = 128 * 64;
  __shared__ f16 As[128 * 64 * ((SPL & 2) ? 2 : 1)];
  __shared__ f16 Bs[128 * 64 * ((SPL & 1) ? 2 : 1)];

  const int tid = threadIdx.x;
  const int wid = tid >> 6, lane = tid & 63;
  const int wm = (wid >> 1) * 32, wn = (wid & 1) * 64;
  const int r = lane & 15, g = lane >> 4;

  f32x4 acc[2][4];
  #pragma unroll
  for (int i = 0; i < 2; i++)
    #pragma unroll
    for (int j = 0; j < 4; j++) acc[i][j] = (f32x4){0.f, 0.f, 0.f, 0.f};

  f16x8 ra0, ra1, rl0, rl1;   // staged A (16 f16 + lo)
  f16x8 rb0, rb1, rbl0, rbl1; // staged B (16 f16 + lo)

  auto loadA = [&](int k0) {
    if (AMODE == HN && AH) {
      const f16* Ah = (const f16*)Ab;
      const int row = tid >> 2, kc = (tid & 3) * 16;
      const long off = (long)(m0 + row) * lda + k0 + kc;
      ra0 = *(const f16x8*)&Ah[off];
      ra1 = *(const f16x8*)&Ah[off + 8];
      if (SPL & 2) { rl0 = *(const f16x8*)&Ah[aLo + off]; rl1 = *(const f16x8*)&Ah[aLo + off + 8]; }
    } else if (AMODE == HN && !AH) {
      const float* Af = (const float*)Ab;
      const int row = tid >> 2, kc = (tid & 3) * 16;
      const float* s = &Af[(long)(m0 + row) * lda + k0 + kc];
      f32x4 v0 = *(const f32x4*)s,       v1 = *(const f32x4*)(s + 4);
      f32x4 v2 = *(const f32x4*)(s + 8), v3 = *(const f32x4*)(s + 12);
      ra0 = (f16x8){(f16)v0.x,(f16)v0.y,(f16)v0.z,(f16)v0.w,(f16)v1.x,(f16)v1.y,(f16)v1.z,(f16)v1.w};
      ra1 = (f16x8){(f16)v2.x,(f16)v2.y,(f16)v2.z,(f16)v2.w,(f16)v3.x,(f16)v3.y,(f16)v3.z,(f16)v3.w};
    } else { // HT (fallback path)
      const int mm = tid & 127, kh = (tid >> 7) * 16;
      if (AH) {
        const f16* s = &((const f16*)Ab)[(long)(k0 + kh) * lda + m0 + mm];
        #pragma unroll
        for (int j = 0; j < 8; j++) ra0[j] = s[(long)j * lda];
        #pragma unroll
        for (int j = 0; j < 8; j++) ra1[j] = s[(long)(j + 8) * lda];
      } else {
        const float* s = &((const float*)Ab)[(long)(k0 + kh) * lda + m0 + mm];
        #pragma unroll
        for (int j = 0; j < 8; j++) ra0[j] = (f16)s[(long)j * lda];
        #pragma unroll
        for (int j = 0; j < 8; j++) ra1[j] = (f16)s[(long)(j + 8) * lda];
      }
    }
  };
  auto storeA = [&]() {
    if (AMODE == HT) {
      const int mm = tid & 127, kh = (tid >> 7) * 16;
      *(f16x8*)&As[swz(mm, mm * 64 + kh)]     = ra0;
      *(f16x8*)&As[swz(mm, mm * 64 + kh + 8)] = ra1;
    } else {
      const int row = tid >> 2, kc = (tid & 3) * 16;
      const int i0 = swz(row, row * 64 + kc), i1 = swz(row, row * 64 + kc + 8);
      *(f16x8*)&As[i0] = ra0;
      *(f16x8*)&As[i1] = ra1;
      if (SPL & 2) { *(f16x8*)&As[HLA + i0] = rl0; *(f16x8*)&As[HLA + i1] = rl1; }
    }
  };
  auto loadB = [&](int k0) {
    const int row = tid >> 2, kc = (tid & 3) * 16;
    const long off = (long)(n0 + row) * ldb + k0 + kc;
    rb0 = *(const f16x8*)&Bh[off];
    rb1 = *(const f16x8*)&Bh[off + 8];
    if (SPL & 1) { rbl0 = *(const f16x8*)&Bh[bLo + off]; rbl1 = *(const f16x8*)&Bh[bLo + off + 8]; }
  };
  auto storeB = [&]() {
    const int row = tid >> 2, kc = (tid & 3) * 16;
    const int i0 = swz(row, row * 64 + kc), i1 = swz(row, row * 64 + kc + 8);
    *(f16x8*)&Bs[i0] = rb0;
    *(f16x8*)&Bs[i1] = rb1;
    if (SPL & 1) { *(f16x8*)&Bs[HLB + i0] = rbl0; *(f16x8*)&Bs[HLB + i1] = rbl1; }
  };

  loadA(0); loadB(0);
  storeA(); storeB();
  __syncthreads();

  const int NT = K >> 6;
  for (int t = 0; t < NT; t++) {
    const bool more = (t + 1 < NT);
    if (more) { loadA((t + 1) << 6); loadB((t + 1) << 6); }  // issue early
    #pragma unroll
    for (int ks = 0; ks < 2; ks++) {
      f16x8 af[2], bf[4], afl[2], bfl[4];
      #pragma unroll
      for (int i = 0; i < 2; i++) {
        const int rw = wm + i * 16 + r;
        const int ix = swz(rw, rw * 64 + ks * 32 + g * 8);
        af[i] = *(const f16x8*)&As[ix];
        if (SPL & 2) afl[i] = *(const f16x8*)&As[HLA + ix];
      }
      #pragma unroll
      for (int j = 0; j < 4; j++) {
        const int rw = wn + j * 16 + r;
        const int ix = swz(rw, rw * 64 + ks * 32 + g * 8);
        bf[j] = *(const f16x8*)&Bs[ix];
        if (SPL & 1) bfl[j] = *(const f16x8*)&Bs[HLB + ix];
      }
      #pragma unroll
      for (int i = 0; i < 2; i++)
        #pragma unroll
        for (int j = 0; j < 4; j++) {
          acc[i][j] = __builtin_amdgcn_mfma_f32_16x16x32_f16(af[i], bf[j], acc[i][j], 0, 0, 0);
          if (SPL & 1)
            acc[i][j] = __builtin_amdgcn_mfma_f32_16x16x32_f16(af[i], bfl[j], acc[i][j], 0, 0, 0);
          if (SPL & 2)
            acc[i][j] = __builtin_amdgcn_mfma_f32_16x16x32_f16(afl[i], bf[j], acc[i][j], 0, 0, 0);
        }
    }
    __syncthreads();
    if (more) { storeA(); storeB(); __syncthreads(); }
  }

  // ---- epilogue: acc map col=lane&15, row=(lane>>4)*4+t
  if (OUTM == OHT) {
    // two-pass 128x64 transpose through Bs, 64B-contiguous column writes
    f16* tile = (f16*)Bs;   // [128 cols][72 pad] = 18KB, fits
    #pragma unroll
    for (int half = 0; half < 2; half++) {
      __syncthreads();
      if ((wm >> 6) == half) {
        #pragma unroll
        for (int i = 0; i < 2; i++)
          #pragma unroll
          for (int j = 0; j < 4; j++) {
            const int rowl = wm + i * 16 + g * 4 - 64 * half;
            const int coll = wn + j * 16 + r;
            #pragma unroll
            for (int t = 0; t < 4; t++) {
              float v = acc[i][j][t];
              if (EPI == EP_ADDRELUH) {
                v += (float)((const f16*)aux1)[(long)(m0 + 64 * half + rowl + t) * 256 + n0 + coll];
                v = v > 0.f ? v : 0.f;
              } else if (EPI == EP_BIAS) { v += bias[n0 + coll]; }
              tile[coll * 72 + rowl + t] = (f16)v;
            }
          }
      }
      __syncthreads();
      const int c2 = tid >> 2, rs = (tid & 3) * 16;
      f16* dst = &((f16*)Cb)[(long)(n0 + c2) * ldc + m0 + 64 * half + rs];
      *(f16x8*)dst       = *(const f16x8*)&tile[c2 * 72 + rs];
      *(f16x8*)(dst + 8) = *(const f16x8*)&tile[c2 * 72 + rs + 8];
    }
  } else {
    #pragma unroll
    for (int i = 0; i < 2; i++) {
      #pragma unroll
      for (int j = 0; j < 4; j++) {
        const int rowb = m0 + wm + i * 16 + g * 4;
        const int col = n0 + wn + j * 16 + r;
        #pragma unroll
        for (int t = 0; t < 4; t++) {
          const int row = rowb + t;
          const long idx = (long)row * ldc + col;
          float v = acc[i][j][t];
          if (EPI == EP_BIAS)          { v += bias[col]; }
          else if (EPI == EP_ADDRELUH) { v += (float)((const f16*)aux1)[(long)row * 256 + col];
                                         v = v > 0.f ? v : 0.f; }
          else if (EPI == EP_AGG)      { v = (v + aux1[idx]) * aux2[row]; }
          if (OUTM == OH) ((f16*)Cb)[idx] = (f16)v;
          else            ((float*)Cb)[idx] = v;
          if (EPI == EP_AGG && Cs) {
            short hh = f2bf(v);
            Cs[idx] = hh;
            Cs[csLo + idx] = f2bf(v - bf2f(hh));
          }
        }
      }
    }
  }
}

// ----- split-bf16 gate GEMM, tile 128x128, BK=64, 8 waves, 16x16x32 MFMA -----
// GM_Z: K=768, q0=copy P1 (inv_s), q1=copy P2 (outv_s), q2=iv*ov from f32 A,A2.
// GM_UR: K=512, q0=copy P1 (cur_s), q1=copy P2 (nv_s).
// GM_M: K=512, q0=r*cur from f32 A(lda),A2, q1=copy P2 (nv_s).
// SE_GRU: fused GRU blend: cur_new = (1-u)*cur_old + u*tanh(acc); u=aux1[row*512+col],
// cur_old=aux2[row*256+col]; writes C (f32), Cs planes (bf16), Ch planes (f16).
template<int AMODE, int EPI>
__global__ __launch_bounds__(512) void ggemm(
    const float* __restrict__ A, const float* __restrict__ A2,
    const short* __restrict__ P1, const short* __restrict__ P2, long pLo,
    const short* __restrict__ Bw, float* __restrict__ C,
    short* __restrict__ Cs, long csLo, f16* __restrict__ Ch, long chLo,
    const float* __restrict__ aux1, const float* __restrict__ aux2, const float* __restrict__ bias,
    int Nd, int K, int lda, int ldb, int ldc, long bLo)
{
  int bxi, byi, bzu;
  xcd_remap(bxi, byi, bzu);
  const int m0 = byi * 128;
  const int n0 = bxi * 128;
  constexpr int HLA = 128 * 64;
  constexpr int HLB = 128 * 64;
  __shared__ short As[128 * 64 * 2];
  __shared__ short Bs[128 * 64 * 2];

  const int tid = threadIdx.x;
  const int wid = tid >> 6, lane = tid & 63;
  const int wm = (wid >> 1) * 32, wn = (wid & 1) * 64;
  const int r = lane & 15, g = lane >> 4;

  f32x4 acc[2][4];
  #pragma unroll
  for (int i = 0; i < 2; i++)
    #pragma unroll
    for (int j = 0; j < 4; j++) acc[i][j] = (f32x4){0.f, 0.f, 0.f, 0.f};

  s16x8 rh0, rh1, rlo0, rlo1;       // staged A (16 bf16 hi + lo)
  s16x8 rbh0, rbh1, rbl0, rbl1;     // staged B

  auto loadA = [&](int k0) {
    const int row = tid >> 2, kc = (tid & 3) * 16;
    const int q = k0 >> 8, kd = (k0 + kc) & 255;
    const long base = (long)(m0 + row) * 256 + kd;
    bool copy; const short* P;
    if (AMODE == GM_Z)       { copy = (q < 2); P = (q == 0) ? P1 : P2; }
    else if (AMODE == GM_UR) { copy = true;    P = (q == 0) ? P1 : P2; }
    else                     { copy = (q == 1); P = P2; }   // GM_M
    if (copy) {
      rh0  = *(const s16x8*)&P[base];
      rh1  = *(const s16x8*)&P[base + 8];
      rlo0 = *(const s16x8*)&P[pLo + base];
      rlo1 = *(const s16x8*)&P[pLo + base + 8];
    } else {
      float x[16];
      if (AMODE == GM_Z) {          // q==2: iv*ov
        #pragma unroll
        for (int u = 0; u < 4; u++) {
          f32x4 a = *(const f32x4*)(A  + base + 4 * u);
          f32x4 b = *(const f32x4*)(A2 + base + 4 * u);
          f32x4 v = a * b;
          x[4*u] = v.x; x[4*u+1] = v.y; x[4*u+2] = v.z; x[4*u+3] = v.w;
        }
      } else {                      // GM_M q==0: r*cur (A pitch lda)
        const long baseA = (long)(m0 + row) * lda + kd;
        #pragma unroll
        for (int u = 0; u < 4; u++) {
          f32x4 a = *(const f32x4*)(A  + baseA + 4 * u);
          f32x4 b = *(const f32x4*)(A2 + base + 4 * u);
          f32x4 v = a * b;
          x[4*u] = v.x; x[4*u+1] = v.y; x[4*u+2] = v.z; x[4*u+3] = v.w;
        }
      }
      short hh[16], ll[16];
      #pragma unroll
      for (int e = 0; e < 16; e++) { hh[e] = f2bf(x[e]); ll[e] = f2bf(x[e] - bf2f(hh[e])); }
      rh0  = (s16x8){hh[0],hh[1],hh[2],hh[3],hh[4],hh[5],hh[6],hh[7]};
      rh1  = (s16x8){hh[8],hh[9],hh[10],hh[11],hh[12],hh[13],hh[14],hh[15]};
      rlo0 = (s16x8){ll[0],ll[1],ll[2],ll[3],ll[4],ll[5],ll[6],ll[7]};
      rlo1 = (s16x8){ll[8],ll[9],ll[10],ll[11],ll[12],ll[13],ll[14],ll[15]};
    }
  };
  auto storeA = [&]() {
    const int row = tid >> 2, kc = (tid & 3) * 16;
    const int i0 = swz(row, row * 64 + kc), i1 = swz(row, row * 64 + kc + 8);
    *(s16x8*)&As[i0] = rh0;
    *(s16x8*)&As[i1] = rh1;
    *(s16x8*)&As[HLA + i0] = rlo0;
    *(s16x8*)&As[HLA + i1] = rlo1;
  };
  auto loadB = [&](int k0) {
    const int row = tid >> 2, kc = (tid & 3) * 16;
    const long off = (long)(n0 + row) * ldb + k0 + kc;
    rbh0 = *(const s16x8*)&Bw[off];
    rbh1 = *(const s16x8*)&Bw[off + 8];
    rbl0 = *(const s16x8*)&Bw[bLo + off];
    rbl1 = *(const s16x8*)&Bw[bLo + off + 8];
  };
  auto storeB = [&]() {
    const int row = tid >> 2, kc = (tid & 3) * 16;
    const int i0 = swz(row, row * 64 + kc), i1 = swz(row, row * 64 + kc + 8);
    *(s16x8*)&Bs[i0] = rbh0;
    *(s16x8*)&Bs[i1] = rbh1;
    *(s16x8*)&Bs[HLB + i0] = rbl0;
    *(s16x8*)&Bs[HLB + i1] = rbl1;
  };

  loadA(0); loadB(0);
  storeA(); storeB();
  __syncthreads();

  const int NT = K >> 6;
  for (int t = 0; t < NT; t++) {
    const bool more = (t + 1 < NT);
    if (more) { loadA((t + 1) << 6); loadB((t + 1) << 6); }
    #pragma unroll
    for (int ks = 0; ks < 2; ks++) {
      s16x8 ah[2], al[2], bh[4], bl[4];
      #pragma unroll
      for (int i = 0; i < 2; i++) {
        const int rw = wm + i * 16 + r;
        const int ix = swz(rw, rw * 64 + ks * 32 + g * 8);
        ah[i] = *(const s16x8*)&As[ix];
        al[i] = *(const s16x8*)&As[HLA + ix];
      }
      #pragma unroll
      for (int j = 0; j < 4; j++) {
        const int rw = wn + j * 16 + r;
        const int ix = swz(rw, rw * 64 + ks * 32 + g * 8);
        bh[j] = *(const s16x8*)&Bs[ix];
        bl[j] = *(const s16x8*)&Bs[HLB + ix];
      }
      #pragma unroll
      for (int i = 0; i < 2; i++)
        #pragma unroll
        for (int j = 0; j < 4; j++) {
          acc[i][j] = __builtin_amdgcn_mfma_f32_16x16x32_bf16(ah[i], bh[j], acc[i][j], 0, 0, 0);
          acc[i][j] = __builtin_amdgcn_mfma_f32_16x16x32_bf16(ah[i], bl[j], acc[i][j], 0, 0, 0);
          acc[i][j] = __builtin_amdgcn_mfma_f32_16x16x32_bf16(al[i], bh[j], acc[i][j], 0, 0, 0);
        }
    }
    __syncthreads();
    if (more) { storeA(); storeB(); __syncthreads(); }
  }

  #pragma unroll
  for (int i = 0; i < 2; i++) {
    #pragma unroll
    for (int j = 0; j < 4; j++) {
      #pragma unroll
      for (int t = 0; t < 4; t++) {
        const int row = m0 + wm + i * 16 + g * 4 + t;
        const int col = n0 + wn + j * 16 + r;
        const long idx = (long)row * ldc + col;
        float v = acc[i][j][t];
        if (EPI == SE_GATE) {
          v += bias[col];
          float z = 1.f / (1.f + __expf(-v));
          const long ix = (long)row * 256 + col;
          v = (1.f - z) * aux1[ix] + z * aux2[ix];
        } else if (EPI == SE_SIG) {
          v = 1.f / (1.f + __expf(-v));
        } else if (EPI == SE_TANH) {
          v = tanhf(v);
        } else { // SE_GRU: cur_new = (1-u)*cur_old + u*tanh(acc)
          float m = tanhf(v);
          float u = aux1[(long)row * 512 + col];
          float co = aux2[(long)row * 256 + col];
          v = (1.f - u) * co + u * m;
        }
        C[idx] = v;
        if ((EPI == SE_GATE || EPI == SE_GRU) && Cs) {
          short hh = f2bf(v);
          Cs[idx] = hh;
          Cs[csLo + idx] = f2bf(v - bf2f(hh));
        }
        if (EPI == SE_GRU && Ch) {
          f16 fh = (f16)v;
          Ch[idx] = fh;
          Ch[chLo + idx] = (f16)(v - (float)fh);
        }
      }
    }
  }
}

// ---------------- small kernels ----------------

// combined z-gate weights: Wc[o][0:256]=W1+W4, [256:512]=W2-W4, [512:768]=W3; split-bf16
__global__ void combine_wz(const float* __restrict__ Wz, short* __restrict__ Wc, long loOff) {
  const int idx = blockIdx.x * 256 + threadIdx.x;   // over 256*768
  const int o = idx / 768, k = idx % 768;
  float v;
  if (k < 256)      v = Wz[o * 1024 + k] + Wz[o * 1024 + 768 + k];
  else if (k < 512) v = Wz[o * 1024 + 256 + (k - 256)] - Wz[o * 1024 + 768 + (k - 256)];
  else              v = Wz[o * 1024 + 512 + (k - 512)];
  short h = f2bf(v);
  Wc[idx] = h;
  Wc[loOff + idx] = f2bf(v - bf2f(h));
}

// Fused adjacency conversion: fp32 [R][C] -> f16 row-major + f16 transposed, plus
// per-n norm partials. SUMDST=false: row sums (e2n). SUMDST=true: column sums (n2e).
template<bool SUMDST>
__global__ void cvt_dual(const float* __restrict__ in, f16* __restrict__ outR,
                         f16* __restrict__ outT, float* __restrict__ part, int R, int C) {
  __shared__ f16 t[64][72];
  __shared__ float sacc[64][4];
  const long boff = (long)blockIdx.z * (long)R * C;
  const int r0 = blockIdx.x * 64, c0 = blockIdx.y * 64;
  const int tid = threadIdx.x;
  const int rl = tid >> 2, cl = (tid & 3) * 16;
  const float* src = in + boff + (long)(r0 + rl) * C + c0 + cl;
  f16 loc[16];
  float s = 0.f;
  #pragma unroll
  for (int u = 0; u < 4; u++) {
    f32x4 v = *(const f32x4*)(src + 4 * u);
    loc[4*u+0] = (f16)v.x; loc[4*u+1] = (f16)v.y; loc[4*u+2] = (f16)v.z; loc[4*u+3] = (f16)v.w;
    if (!SUMDST) s += v.x + v.y + v.z + v.w;
  }
  f16* dR = outR + boff + (long)(r0 + rl) * C + c0 + cl;
  *(f16x8*)dR       = *(const f16x8*)&loc[0];
  *(f16x8*)(dR + 8) = *(const f16x8*)&loc[8];
  *(f16x8*)&t[rl][cl]     = *(const f16x8*)&loc[0];
  *(f16x8*)&t[rl][cl + 8] = *(const f16x8*)&loc[8];
  if (!SUMDST) sacc[rl][tid & 3] = s;
  __syncthreads();
  const int cl2 = tid >> 2, rl2 = (tid & 3) * 16;
  f16x8 o0, o1;
  #pragma unroll
  for (int v = 0; v < 8; v++) { o0[v] = t[rl2 + v][cl2]; o1[v] = t[rl2 + 8 + v][cl2]; }
  if (SUMDST) {
    float s2 = 0.f;
    #pragma unroll
    for (int v = 0; v < 8; v++) s2 += (float)o0[v] + (float)o1[v];
    sacc[cl2][tid & 3] = s2;
  }
  f16* dT = outT + boff + (long)(c0 + cl2) * R + r0 + rl2;
  *(f16x8*)dT = o0;
  *(f16x8*)(dT + 8) = o1;
  __syncthreads();
  if (tid < 64) {
    float tot = sacc[tid][0] + sacc[tid][1] + sacc[tid][2] + sacc[tid][3];
    const int slot = SUMDST ? blockIdx.x : blockIdx.y;
    const int n    = (SUMDST ? c0 : r0) + tid;
    part[((long)blockIdx.z * 64 + slot) * Nn + n] = tot;
  }
}

__global__ void colfin64(const float* __restrict__ part, float* __restrict__ rn) {
  const int i = blockIdx.x * 256 + threadIdx.x;   // over B*N
  const int b = i >> 11, n = i & 2047;
  float s = 0.f;
  for (int c = 0; c < 64; c++) s += part[((long)b * 64 + c) * Nn + n];
  rn[i] = 1.f / (1.f + s);
}

// fallback-mode norm kernels (read fp32 adjacency)
__global__ void rowsum_kernel(const float* __restrict__ e2n, float* __restrict__ out) {
  const int gw = blockIdx.x * 4 + (threadIdx.x >> 6);
  const int lane = threadIdx.x & 63;
  const float* p = e2n + (long)gw * Ee;
  float s = 0.f;
  for (int e = lane; e < Ee; e += 64) s += p[e];
  #pragma unroll
  for (int off = 32; off; off >>= 1) s += __shfl_down(s, off);
  if (lane == 0) out[gw] = 1.f / (1.f + s);
}
__global__ void colsum_kernel(const float* __restrict__ n2e, float* __restrict__ part) {
  const int n = blockIdx.x * 256 + threadIdx.x;
  const int c = blockIdx.y, b = blockIdx.z;
  const float* p = n2e + (long)b * Ee * Nn + (long)c * 256 * Nn + n;
  float s = 0.f;
  for (int e = 0; e < 256; e++) s += p[(long)e * Nn];
  part[((long)b * 16 + c) * Nn + n] = s;
}
__global__ void colfin16(const float* __restrict__ part, float* __restrict__ rni) {
  const int i = blockIdx.x * 256 + threadIdx.x;
  const int b = i >> 11, n = i & 2047;
  float s = 0.f;
  #pragma unroll
  for (int c = 0; c < 16; c++) s += part[((long)b * 16 + c) * Nn + n];
  rni[i] = 1.f / (1.f + s);
}

__global__ void cvt_half(const float* __restrict__ src, f16* __restrict__ dst) {
  const long i4 = (long)blockIdx.x * 256 + threadIdx.x;
  f32x4 v = *(const f32x4*)&src[i4 * 4];
  *(f16x4*)&dst[i4 * 4] = (f16x4){(f16)v.x, (f16)v.y, (f16)v.z, (f16)v.w};
}

__global__ void cvt_half_split(const float* __restrict__ src, f16* __restrict__ dst, long loOff) {
  const long i4 = (long)blockIdx.x * 256 + threadIdx.x;
  f32x4 v = *(const f32x4*)&src[i4 * 4];
  f16x4 h = {(f16)v.x, (f16)v.y, (f16)v.z, (f16)v.w};
  *(f16x4*)&dst[i4 * 4] = h;
  f16x4 l = {(f16)(v.x - (float)h[0]), (f16)(v.y - (float)h[1]),
             (f16)(v.z - (float)h[2]), (f16)(v.w - (float)h[3])};
  *(f16x4*)&dst[loOff + i4 * 4] = l;
}

// fp32 -> split-bf16 (hi plane at dst, lo at dst+loOff)
__global__ void cvt_bf_split(const float* __restrict__ src, short* __restrict__ dst, long loOff) {
  const long i4 = (long)blockIdx.x * 256 + threadIdx.x;
  f32x4 v = *(const f32x4*)&src[i4 * 4];
  s16x4 h = { f2bf(v.x), f2bf(v.y), f2bf(v.z), f2bf(v.w) };
  *(s16x4*)&dst[i4 * 4] = h;
  s16x4 l = { f2bf(v.x - bf2f(h.x)), f2bf(v.y - bf2f(h.y)),
              f2bf(v.z - bf2f(h.z)), f2bf(v.w - bf2f(h.w)) };
  *(s16x4*)&dst[loOff + i4 * 4] = l;
}

__global__ void init_cur(const float* __restrict__ node_vec, float* __restrict__ cur,
                         f16* __restrict__ cur_h, long loOff,
                         short* __restrict__ cur_s, long sLo) {
  const long i4 = (long)blockIdx.x * 256 + threadIdx.x;
  f32x4 v = *(const f32x4*)&node_vec[i4 * 4];
  *(f32x4*)&cur[i4 * 4] = v;
  f16x4 h = {(f16)v.x, (f16)v.y, (f16)v.z, (f16)v.w};
  *(f16x4*)&cur_h[i4 * 4] = h;
  f16x4 l = {(f16)(v.x - (float)h[0]), (f16)(v.y - (float)h[1]),
             (f16)(v.z - (float)h[2]), (f16)(v.w - (float)h[3])};
  *(f16x4*)&cur_h[loOff + i4 * 4] = l;
  s16x4 bh = { f2bf(v.x), f2bf(v.y), f2bf(v.z), f2bf(v.w) };
  *(s16x4*)&cur_s[i4 * 4] = bh;
  s16x4 bl = { f2bf(v.x - bf2f(bh.x)), f2bf(v.y - bf2f(bh.y)),
               f2bf(v.z - bf2f(bh.z)), f2bf(v.w - bf2f(bh.w)) };
  *(s16x4*)&cur_s[sLo + i4 * 4] = bl;
}

// cur [B*N,256] f32 -> cur_hT hi/lo planes [B][256][2048] halves
__global__ void transposeT(const float* __restrict__ cur, f16* __restrict__ curT, long loOff) {
  __shared__ f16 th[64][72];
  __shared__ f16 tl[64][72];
  const int b = blockIdx.z, nt = blockIdx.x * 64, dt = blockIdx.y * 64;
  const int tid = threadIdx.x;
  const int nl = tid >> 2, d0 = (tid & 3) * 16;
  const float* src = cur + ((long)b * Nn + nt + nl) * 256 + dt + d0;
  #pragma unroll
  for (int u = 0; u < 4; u++) {
    f32x4 v = *(const f32x4*)(src + 4 * u);
    f16x4 h = {(f16)v.x, (f16)v.y, (f16)v.z, (f16)v.w};
    *(f16x4*)&th[nl][d0 + 4 * u] = h;
    f16x4 l = {(f16)(v.x - (float)h[0]), (f16)(v.y - (float)h[1]),
               (f16)(v.z - (float)h[2]), (f16)(v.w - (float)h[3])};
    *(f16x4*)&tl[nl][d0 + 4 * u] = l;
  }
  __syncthreads();
  const int dl = tid >> 2, n0l = (tid & 3) * 16;
  f16x8 o0, o1, p0, p1;
  #pragma unroll
  for (int v = 0; v < 8; v++) {
    o0[v] = th[n0l + v][dl];     o1[v] = th[n0l + 8 + v][dl];
    p0[v] = tl[n0l + v][dl];     p1[v] = tl[n0l + 8 + v][dl];
  }
  f16* dst = curT + (long)b * (256 * Nn) + (long)(dt + dl) * Nn + nt + n0l;
  *(f16x8*)dst = o0;
  *(f16x8*)(dst + 8) = o1;
  *(f16x8*)(dst + loOff) = p0;
  *(f16x8*)(dst + loOff + 8) = p1;
}

__global__ void maxpool1(const float* __restrict__ pooled, float* __restrict__ part) {
  const int d = threadIdx.x, c = blockIdx.x, b = blockIdx.y;
  const float* p = pooled + ((long)b * Nn + c * 256) * Dd + d;
  float m = -INFINITY;
  for (int n = 0; n < 256; n++) m = fmaxf(m, p[(long)n * Dd]);
  part[(b * 8 + c) * Dd + d] = m;
}
__global__ void maxpool2(const float* __restrict__ part, float* __restrict__ out1) {
  const int d = threadIdx.x, b = blockIdx.x;
  float m = -INFINITY;
  #pragma unroll
  for (int c = 0; c < 8; c++) m = fmaxf(m, part[(b * 8 + c) * Dd + d]);
  out1[b * Dd + d] = m;
}
__global__ void transpose_out(const float* __restrict__ cur, float* __restrict__ out0) {
  const long i = (long)blockIdx.x * 256 + threadIdx.x;
  const int d = i & 255;
  const long nb = i >> 8;
  const int b = nb & 7;
  const long n = nb >> 3;
  out0[i] = cur[((long)b * Nn + n) * Dd + d];
}

extern "C" void kernel_launch(void* const* d_in, const int* in_sizes, int n_in,
                              void* d_out, int out_size, void* d_ws, size_t ws_size,
                              hipStream_t stream) {
  const float* node_vec = (const float*)d_in[0];
  const float* edge_vec = (const float*)d_in[1];
  const float* n2e      = (const float*)d_in[2];   // [B,E,N]
  const float* e2n      = (const float*)d_in[3];   // [B,N,E]
  const float* W_fuse   = (const float*)d_in[5];   // [256,512]
  const float* b_fuse   = (const float*)d_in[6];
  const float* W_z      = (const float*)d_in[7];   // [256,1024]
  const float* b_z      = (const float*)d_in[8];
  const float* W_u      = (const float*)d_in[9];
  const float* W_r      = (const float*)d_in[10];
  const float* W_m      = (const float*)d_in[11];
  const float* W_max    = (const float*)d_in[12];  // [256,256]

  const long ND  = (long)Bb * Nn * Dd;   // 4194304
  const long EDb = (long)Ee * Dd;        // 1048576
  const long NDb = (long)Nn * Dd;        // 524288
  const long ED  = (long)Bb * EDb;       // 8388608
  const long ADJb = (long)Ee * Nn;       // 8388608 (per batch)
  const long ADJ = (long)Bb * ADJb;      // 67108864
  const int  BN  = Bb * Nn;

  // ---- arena ----
  char* p = (char*)d_ws;
  auto alloc = [&](size_t bytes) { char* r = p; p += (bytes + 255) & ~(size_t)255; return r; };

  const size_t need_full =
      (size_t)4 * ADJ * 2
      + (size_t)ED * 2                        // ev_h
      + (size_t)4 * ED * 2                    // E1h2, E2T2
      + (size_t)ED * 2                        // EVWh (f16)
      + (size_t)2 * 2 * ND * 2                // cur_hA/B (planes)
      + (size_t)2 * ND * 2                    // cur_hT
      + (size_t)(2 * 131072 + 2 * 65536) * 2
      + (size_t)(2 * 262144 + 2 * 131072) * 2 // Wur_s, Wm_s
      + (size_t)2 * 196608 * 2                // Wzc_s
      + (size_t)(2 + 2 + 1) * ND * 4          // curA, curB, outv|inv, nv
      + (size_t)BN * 512 * 4                  // urb
      + (size_t)(2 * BN + 2 * 64 * BN) * 4
      + (size_t)(4 * ND + 2 * ND + 2 * 2 * ND) * 2  // outinv_s, nv_s, cur_sA/B
      + 64 * 1024;
  const bool full = ws_size >= need_full;

  f16 *adjEO = nullptr, *adjAG = nullptr;
  f16 *n2e_h = nullptr, *e2n_hT = nullptr, *e2n_h = nullptr, *n2e_hT = nullptr;
  if (full) {
    adjEO = (f16*)alloc((size_t)2 * ADJ * 2);
    adjAG = (f16*)alloc((size_t)2 * ADJ * 2);
    n2e_h = adjEO;  e2n_hT = adjEO + ADJ;
    e2n_h = adjAG;  n2e_hT = adjAG + ADJ;
  }
  f16* ev_h    = (f16*)alloc(ED * 2);
  f16* E1h2    = (f16*)alloc((size_t)2 * ED * 2);  // 16 slabs [Ee][256]
  f16* E2T2    = (f16*)alloc((size_t)2 * ED * 2);  // 16 slabs [256][Ee]
  f16* EVWh    = (f16*)alloc(ED * 2);              // 8 slabs [Ee][256] f16
  f16* cur_hA  = (f16*)alloc(2 * ND * 2);
  f16* cur_hB  = (f16*)alloc(2 * ND * 2);
  f16* cur_hT  = (f16*)alloc(2 * ND * 2);
  f16* Wf_h    = (f16*)alloc(2 * 131072 * 2);
  f16* Wmax_h  = (f16*)alloc(2 * 65536 * 2);
  short* Wur_s = (short*)alloc((size_t)2 * 262144 * 2);
  short* Wm_s  = (short*)alloc((size_t)2 * 131072 * 2);
  short* Wzc_s = (short*)alloc((size_t)2 * 196608 * 2);   // combined z weights [256][768] hi+lo
  float* curA  = (float*)alloc(ND * 4);
  float* curB  = (float*)alloc(ND * 4);
  float* outv  = (float*)alloc(2 * ND * 4);        // outv|inv contiguous
  float* inv   = outv + ND;
  float* nv    = (float*)alloc(ND * 4);
  float* urb   = (float*)alloc((size_t)BN * 512 * 4);
  float* rno   = (float*)alloc(2 * BN * 4);        // rno|rni contiguous
  float* rni   = rno + BN;
  float* rnopart = (float*)alloc((size_t)64 * BN * 4);
  float* rnipart = (float*)alloc((size_t)64 * BN * 4);
  float* maxpart = (float*)alloc(BN * 4);
  short* outinv_s = (short*)alloc((size_t)4 * ND * 2);  // hi [2ND] + lo [2ND]
  short* nv_s     = (short*)alloc((size_t)2 * ND * 2);  // hi [ND] + lo [ND]
  short* cur_sA   = (short*)alloc((size_t)2 * ND * 2);  // hi [ND] + lo [ND]
  short* cur_sB   = (short*)alloc((size_t)2 * ND * 2);  // hi [ND] + lo [ND]
  short* outv_s   = outinv_s;
  short* inv_s    = outinv_s + ND;

  float* out0 = (float*)d_out;
  float* out1 = out0 + ND;

  // ---- one-time conversions + norms + transposed adjacency caches ----
  if (full) {
    cvt_dual<false><<<dim3(Nn / 64, Ee / 64, Bb), 256, 0, stream>>>(
        e2n, e2n_h, e2n_hT, rnopart, Nn, Ee);
    cvt_dual<true><<<dim3(Ee / 64, Nn / 64, Bb), 256, 0, stream>>>(
        n2e, n2e_h, n2e_hT, rnipart, Ee, Nn);
    colfin64<<<BN / 256, 256, 0, stream>>>(rnopart, rno);
    colfin64<<<BN / 256, 256, 0, stream>>>(rnipart, rni);
  } else {
    colsum_kernel<<<dim3(Nn / 256, 16, Bb), 256, 0, stream>>>(n2e, rnipart);
    colfin16<<<BN / 256, 256, 0, stream>>>(rnipart, rni);
    rowsum_kernel<<<BN / 4, 256, 0, stream>>>(e2n, rno);
  }
  cvt_half<<<(int)(ED / 1024), 256, 0, stream>>>(edge_vec, ev_h);
  cvt_half_split<<<131072 / 1024, 256, 0, stream>>>(W_fuse, Wf_h, 131072);
  cvt_half_split<<<65536 / 1024, 256, 0, stream>>>(W_max, Wmax_h, 65536);
  combine_wz<<<196608 / 256, 256, 0, stream>>>(W_z, Wzc_s, 196608);
  cvt_bf_split<<<131072 / 1024, 256, 0, stream>>>(W_u, Wur_s, 262144);
  cvt_bf_split<<<131072 / 1024, 256, 0, stream>>>(W_r, Wur_s + 131072, 262144);
  cvt_bf_split<<<131072 / 1024, 256, 0, stream>>>(W_m, Wm_s, 131072);
  init_cur<<<(int)(ND / 1024), 256, 0, stream>>>(node_vec, curA, cur_hA, ND, cur_sA, ND);
  transposeT<<<dim3(Nn / 64, 4, Bb), 256, 0, stream>>>(curA, cur_hT, ND);

  // EVWh = ev @ Wf[:,256:]^T + b_fuse  (hop-invariant, K=256, split-B) -> f16
  hgemm<HN, true, 1, EP_BIAS, OH><<<dim3(2, Ee / 128, Bb), 512, 0, stream>>>(
      ev_h, Wf_h + 256, EVWh, nullptr, nullptr, b_fuse,
      Ee, 256, 256, 256, 512, 256, EDb, 0, EDb, 0, 0, 0, 131072, 0, 0, nullptr, 0);

  float* curP = curA;  f16* curhP = cur_hA;  short* cursP = cur_sA;
  float* curN = curB;  f16* curhN = cur_hB;  short* cursN = cur_sB;

  for (int h = 0; h < HOPS; h++) {
    if (full) {
      // EO1|EI1 = (n2e_h | e2n_hT) @ cur -> E1h2 ; B=cur_hT split, wraps@8
      hgemm<HN, true, 1, EP_NONE, OH><<<dim3(2, Ee / 128, 2 * Bb), 512, 0, stream>>>(
          adjEO, cur_hT, E1h2, nullptr, nullptr, nullptr,
          Ee, 256, Nn, Nn, Nn, 256, ADJb, NDb, EDb, 0, 0, 0, ND, 7, 0, nullptr, 0);
      // EO2|EI2 = relu(E1 @ Wf1^T + EVWh) -> E2T2 (f16-T); sAux1 in f32 units = EDb/2
      hgemm<HN, true, 1, EP_ADDRELUH, OHT><<<dim3(2, Ee / 128, 2 * Bb), 512, 0, stream>>>(
          E1h2, Wf_h, E2T2, (const float*)EVWh, nullptr, nullptr,
          Ee, 256, 256, 256, 512, Ee, EDb, 0, EDb, EDb / 2, 0, 0, 131072, 0, 7, nullptr, 0);
      // out|in = ((e2n_h | n2e_hT) @ E2 + cur) * (rno|rni) -> outv|inv (+ split-bf16 planes)
      hgemm<HN, true, 0, EP_AGG, OF><<<dim3(2, Nn / 128, 2 * Bb), 512, 0, stream>>>(
          adjAG, E2T2, outv, curP, rno, nullptr,
          Nn, 256, Ee, Ee, Ee, 256, ADJb, EDb, NDb, NDb, (long)Nn, 0, 0, 15, 7,
          outinv_s, 2 * ND);
    } else {
      hgemm<HN, false, 1, EP_NONE, OH><<<dim3(2, Ee / 128, Bb), 512, 0, stream>>>(
          n2e, cur_hT, E1h2, nullptr, nullptr, nullptr,
          Ee, 256, Nn, Nn, Nn, 256, ADJb, NDb, EDb, 0, 0, 0, ND, 7, 0, nullptr, 0);
      hgemm<HT, false, 1, EP_NONE, OH><<<dim3(2, Ee / 128, Bb), 512, 0, stream>>>(
          e2n, cur_hT, E1h2 + ED, nullptr, nullptr, nullptr,
          Ee, 256, Nn, Ee, Nn, 256, ADJb, NDb, EDb, 0, 0, 0, ND, 7, 0, nullptr, 0);
      hgemm<HN, true, 1, EP_ADDRELUH, OHT><<<dim3(2, Ee / 128, 2 * Bb), 512, 0, stream>>>(
          E1h2, Wf_h, E2T2, (const float*)EVWh, nullptr, nullptr,
          Ee, 256, 256, 256, 512, Ee, EDb, 0, EDb, EDb / 2, 0, 0, 131072, 0, 7, nullptr, 0);
      hgemm<HN, false, 0, EP_AGG, OF><<<dim3(2, Nn / 128, Bb), 512, 0, stream>>>(
          e2n, E2T2, outv, curP, rno, nullptr,
          Nn, 256, Ee, Ee, Ee, 256, (long)Nn * Ee, EDb, NDb, NDb, (long)Nn, 0, 0, 15, 7,
          outinv_s, 2 * ND);
      hgemm<HT, false, 0, EP_AGG, OF><<<dim3(2, Nn / 128, Bb), 512, 0, stream>>>(
          n2e, E2T2 + ED, inv, curP, rni, nullptr,
          Nn, 256, Ee, Nn, Ee, 256, (long)Ee * Nn, EDb, NDb, NDb, (long)Nn, 0, 0, 15, 7,
          outinv_s + ND, 2 * ND);
    }
    // gated fusion: nv = (1-z)*inv + z*outv  [split-bf16, combined weights K=768]
    ggemm<GM_Z, SE_GATE><<<dim3(2, BN / 128, 1), 512, 0, stream>>>(
        inv, outv, inv_s, outv_s, 2 * ND, Wzc_s, nv, nv_s, ND, nullptr, 0,
        inv, outv, b_z, 256, 768, 256, 768, 256, 196608);
    // u|r = sigmoid(concat(cur,nv) @ [W_u;W_r]^T) -> urb [BN,512]  (pure-copy A)
    ggemm<GM_UR, SE_SIG><<<dim3(4, BN / 128, 1), 512, 0, stream>>>(
        nullptr, nullptr, cursP, nv_s, ND, Wur_s, urb, nullptr, 0, nullptr, 0,
        nullptr, nullptr, nullptr, 512, 512, 0, 512, 512, 262144);
    // m = tanh(concat(r*cur, nv) @ W_m^T); fused GRU blend -> curN (+ planes)
    ggemm<GM_M, SE_GRU><<<dim3(2, BN / 128, 1), 512, 0, stream>>>(
        urb + 256, curP, nullptr, nv_s, ND, Wm_s, curN, cursN, ND, curhN, ND,
        urb, curP, nullptr, 256, 512, 512, 512, 256, 131072);
    if (h < HOPS - 1)
      transposeT<<<dim3(Nn / 64, 4, Bb), 256, 0, stream>>>(curN, cur_hT, ND);
    // swap buffers
    { float* tf = curP; curP = curN; curN = tf; }
    { f16* th2 = curhP; curhP = curhN; curhN = th2; }
    { short* ts = cursP; cursP = cursN; cursN = ts; }
  }

  // pooled = cur @ W_max^T -> urb (f32); both operands split
  hgemm<HN, true, 3, EP_NONE, OF><<<dim3(2, BN / 128, 1), 512, 0, stream>>>(
      curhP, Wmax_h, urb, nullptr, nullptr, nullptr,
      BN, 256, 256, 256, 256, 256, 0, 0, 0, 0, 0, ND, 65536, 0, 0, nullptr, 0);
  maxpool1<<<dim3(8, Bb), 256, 0, stream>>>(urb, maxpart);
  maxpool2<<<Bb, 256, 0, stream>>>(maxpart, out1);

  transpose_out<<<(int)(ND / 256), 256, 0, stream>>>(curP, out0);
}

// Round 19
// 1567.291 us; speedup vs baseline: 1.0166x; 1.0166x over previous
//
#include <hip/hip_runtime.h>
#include <math.h>

#define Bb 8
#define Nn 2048
#define Ee 4096
#define Dd 256
#define HOPS 3

typedef __attribute__((ext_vector_type(4))) float f32x4;
typedef _Float16 f16;
typedef __attribute__((ext_vector_type(8))) _Float16 f16x8;
typedef __attribute__((ext_vector_type(4))) _Float16 f16x4;
typedef __attribute__((ext_vector_type(8))) short s16x8;
typedef __attribute__((ext_vector_type(4))) short s16x4;

__device__ __forceinline__ short f2bf(float f){
  union{float f; unsigned u;} x; x.f=f;
  unsigned r = (x.u + 0x7fffu + ((x.u>>16)&1u)) >> 16;
  return (short)r;
}
__device__ __forceinline__ float bf2f(short h){
  union{unsigned u; float f;} x; x.u = ((unsigned)(unsigned short)h) << 16; return x.f;
}
// XOR-swizzle on 16B granules within a row-major [R][64] 16-bit LDS tile (T2)
__device__ __forceinline__ int swz(int row, int idx){ return idx ^ ((row & 7) << 3); }

enum { HN=0, HT=1 };                                  // hgemm A modes
enum { OF=0, OH=1, OHT=2 };                           // output: f32 / f16 / f16-transposed
enum { EP_NONE=0, EP_BIAS, EP_ADDRELUH, EP_AGG };     // hgemm epilogues (ADDRELUH: f16 aux)
enum { GM_Z=0, GM_UR, GM_M };                         // ggemm A modes
enum { SE_GATE=0, SE_SIG, SE_TANH };                  // ggemm epilogues

// T1: bijective XCD-aware blockIdx remap (all grids have nwg % 8 == 0)
__device__ __forceinline__ void xcd_remap(int& bx, int& by, int& bz) {
  const int nx = gridDim.x, ny = gridDim.y;
  const int nwg = nx * ny * gridDim.z;
  const int lin0 = blockIdx.x + nx * (blockIdx.y + ny * blockIdx.z);
  const int cpx = nwg >> 3;
  const int lin = (lin0 & 7) * cpx + (lin0 >> 3);
  bx = lin % nx;
  const int t1 = lin / nx;
  by = t1 % ny;
  bz = t1 / ny;
}

// -------------- fp16 MFMA GEMM: tile 128x128, BK=64, 8 waves (4x2), 512 thr --------------
// 16x16x32 MFMA (0 bank conflicts). Reg-staged 2-phase. C map: col=lane&15, row=(lane>>4)*4+t.
// Cs (optional, EP_AGG/OF): also emit split-bf16 planes of C (hi at Cs, lo at Cs+csLo).
template<int AMODE, bool AH, int SPL, int EPI, int OUTM>
__global__ __launch_bounds__(512) void hgemm(
    const void* __restrict__ Av, const f16* __restrict__ Bh, void* __restrict__ Cv,
    const float* __restrict__ aux1, const float* __restrict__ aux2,
    const float* __restrict__ bias,
    int M, int Nd, int K, int lda, int ldb, int ldc,
    long sA, long sB, long sC, long sAux1, long sAux2,
    long aLo, long bLo, int maskB, int mask1,
    short* __restrict__ Cs, long csLo)
{
  int bxi, byi, bz;
  xcd_remap(bxi, byi, bz);
  const char* Ab = (const char*)Av + (AH ? bz * sA * 2 : bz * sA * 4);
  Bh += (long)(bz & maskB) * sB;
  char* Cb = (char*)Cv + ((OUTM == OF) ? bz * sC * 4 : bz * sC * 2);
  if (Cs) Cs += (long)bz * sC;
  if (aux1) aux1 += (long)(bz & mask1) * sAux1;   // for EP_ADDRELUH: sAux1 in f32 units (= f16 elems / 2)
  if (aux2) aux2 += bz * sAux2;
  const int m0 = byi * 128;
  const int n0 = bxi * 128;

  constexpr int HLA = 128 * 64;
  constexpr int HLB = 128 * 64;
  __shared__ f16 As[128 * 64 * ((SPL & 2) ? 2 : 1)];
  __shared__ f16 Bs[128 * 64 * ((SPL & 1) ? 2 : 1)];

  const int tid = threadIdx.x;
  const int wid = tid >> 6, lane = tid & 63;
  const int wm = (wid >> 1) * 32, wn = (wid & 1) * 64;
  const int r = lane & 15, g = lane >> 4;

  f32x4 acc[2][4];
  #pragma unroll
  for (int i = 0; i < 2; i++)
    #pragma unroll
    for (int j = 0; j < 4; j++) acc[i][j] = (f32x4){0.f, 0.f, 0.f, 0.f};

  f16x8 ra0, ra1, rl0, rl1;   // staged A (16 f16 + lo)
  f16x8 rb0, rb1, rbl0, rbl1; // staged B (16 f16 + lo)

  auto loadA = [&](int k0) {
    if (AMODE == HN && AH) {
      const f16* Ah = (const f16*)Ab;
      const int row = tid >> 2, kc = (tid & 3) * 16;
      const long off = (long)(m0 + row) * lda + k0 + kc;
      ra0 = *(const f16x8*)&Ah[off];
      ra1 = *(const f16x8*)&Ah[off + 8];
      if (SPL & 2) { rl0 = *(const f16x8*)&Ah[aLo + off]; rl1 = *(const f16x8*)&Ah[aLo + off + 8]; }
    } else if (AMODE == HN && !AH) {
      const float* Af = (const float*)Ab;
      const int row = tid >> 2, kc = (tid & 3) * 16;
      const float* s = &Af[(long)(m0 + row) * lda + k0 + kc];
      f32x4 v0 = *(const f32x4*)s,       v1 = *(const f32x4*)(s + 4);
      f32x4 v2 = *(const f32x4*)(s + 8), v3 = *(const f32x4*)(s + 12);
      ra0 = (f16x8){(f16)v0.x,(f16)v0.y,(f16)v0.z,(f16)v0.w,(f16)v1.x,(f16)v1.y,(f16)v1.z,(f16)v1.w};
      ra1 = (f16x8){(f16)v2.x,(f16)v2.y,(f16)v2.z,(f16)v2.w,(f16)v3.x,(f16)v3.y,(f16)v3.z,(f16)v3.w};
    } else { // HT (fallback path)
      const int mm = tid & 127, kh = (tid >> 7) * 16;
      if (AH) {
        const f16* s = &((const f16*)Ab)[(long)(k0 + kh) * lda + m0 + mm];
        #pragma unroll
        for (int j = 0; j < 8; j++) ra0[j] = s[(long)j * lda];
        #pragma unroll
        for (int j = 0; j < 8; j++) ra1[j] = s[(long)(j + 8) * lda];
      } else {
        const float* s = &((const float*)Ab)[(long)(k0 + kh) * lda + m0 + mm];
        #pragma unroll
        for (int j = 0; j < 8; j++) ra0[j] = (f16)s[(long)j * lda];
        #pragma unroll
        for (int j = 0; j < 8; j++) ra1[j] = (f16)s[(long)(j + 8) * lda];
      }
    }
  };
  auto storeA = [&]() {
    if (AMODE == HT) {
      const int mm = tid & 127, kh = (tid >> 7) * 16;
      *(f16x8*)&As[swz(mm, mm * 64 + kh)]     = ra0;
      *(f16x8*)&As[swz(mm, mm * 64 + kh + 8)] = ra1;
    } else {
      const int row = tid >> 2, kc = (tid & 3) * 16;
      const int i0 = swz(row, row * 64 + kc), i1 = swz(row, row * 64 + kc + 8);
      *(f16x8*)&As[i0] = ra0;
      *(f16x8*)&As[i1] = ra1;
      if (SPL & 2) { *(f16x8*)&As[HLA + i0] = rl0; *(f16x8*)&As[HLA + i1] = rl1; }
    }
  };
  auto loadB = [&](int k0) {
    const int row = tid >> 2, kc = (tid & 3) * 16;
    const long off = (long)(n0 + row) * ldb + k0 + kc;
    rb0 = *(const f16x8*)&Bh[off];
    rb1 = *(const f16x8*)&Bh[off + 8];
    if (SPL & 1) { rbl0 = *(const f16x8*)&Bh[bLo + off]; rbl1 = *(const f16x8*)&Bh[bLo + off + 8]; }
  };
  auto storeB = [&]() {
    const int row = tid >> 2, kc = (tid & 3) * 16;
    const int i0 = swz(row, row * 64 + kc), i1 = swz(row, row * 64 + kc + 8);
    *(f16x8*)&Bs[i0] = rb0;
    *(f16x8*)&Bs[i1] = rb1;
    if (SPL & 1) { *(f16x8*)&Bs[HLB + i0] = rbl0; *(f16x8*)&Bs[HLB + i1] = rbl1; }
  };

  loadA(0); loadB(0);
  storeA(); storeB();
  __syncthreads();

  const int NT = K >> 6;
  for (int t = 0; t < NT; t++) {
    const bool more = (t + 1 < NT);
    if (more) { loadA((t + 1) << 6); loadB((t + 1) << 6); }  // issue early
    #pragma unroll
    for (int ks = 0; ks < 2; ks++) {
      f16x8 af[2], bf[4], afl[2], bfl[4];
      #pragma unroll
      for (int i = 0; i < 2; i++) {
        const int rw = wm + i * 16 + r;
        const int ix = swz(rw, rw * 64 + ks * 32 + g * 8);
        af[i] = *(const f16x8*)&As[ix];
        if (SPL & 2) afl[i] = *(const f16x8*)&As[HLA + ix];
      }
      #pragma unroll
      for (int j = 0; j < 4; j++) {
        const int rw = wn + j * 16 + r;
        const int ix = swz(rw, rw * 64 + ks * 32 + g * 8);
        bf[j] = *(const f16x8*)&Bs[ix];
        if (SPL & 1) bfl[j] = *(const f16x8*)&Bs[HLB + ix];
      }
      #pragma unroll
      for (int i = 0; i < 2; i++)
        #pragma unroll
        for (int j = 0; j < 4; j++) {
          acc[i][j] = __builtin_amdgcn_mfma_f32_16x16x32_f16(af[i], bf[j], acc[i][j], 0, 0, 0);
          if (SPL & 1)
            acc[i][j] = __builtin_amdgcn_mfma_f32_16x16x32_f16(af[i], bfl[j], acc[i][j], 0, 0, 0);
          if (SPL & 2)
            acc[i][j] = __builtin_amdgcn_mfma_f32_16x16x32_f16(afl[i], bf[j], acc[i][j], 0, 0, 0);
        }
    }
    __syncthreads();
    if (more) { storeA(); storeB(); __syncthreads(); }
  }

  // ---- epilogue: acc map col=lane&15, row=(lane>>4)*4+t
  if (OUTM == OHT) {
    // two-pass 128x64 transpose through Bs, 64B-contiguous column writes
    f16* tile = (f16*)Bs;   // [128 cols][72 pad] = 18KB, fits
    #pragma unroll
    for (int half = 0; half < 2; half++) {
      __syncthreads();
      if ((wm >> 6) == half) {
        #pragma unroll
        for (int i = 0; i < 2; i++)
          #pragma unroll
          for (int j = 0; j < 4; j++) {
            const int rowl = wm + i * 16 + g * 4 - 64 * half;
            const int coll = wn + j * 16 + r;
            #pragma unroll
            for (int t = 0; t < 4; t++) {
              float v = acc[i][j][t];
              if (EPI == EP_ADDRELUH) {
                v += (float)((const f16*)aux1)[(long)(m0 + 64 * half + rowl + t) * 256 + n0 + coll];
                v = v > 0.f ? v : 0.f;
              } else if (EPI == EP_BIAS) { v += bias[n0 + coll]; }
              tile[coll * 72 + rowl + t] = (f16)v;
            }
          }
      }
      __syncthreads();
      const int c2 = tid >> 2, rs = (tid & 3) * 16;
      f16* dst = &((f16*)Cb)[(long)(n0 + c2) * ldc + m0 + 64 * half + rs];
      *(f16x8*)dst       = *(const f16x8*)&tile[c2 * 72 + rs];
      *(f16x8*)(dst + 8) = *(const f16x8*)&tile[c2 * 72 + rs + 8];
    }
  } else {
    #pragma unroll
    for (int i = 0; i < 2; i++) {
      #pragma unroll
      for (int j = 0; j < 4; j++) {
        const int rowb = m0 + wm + i * 16 + g * 4;
        const int col = n0 + wn + j * 16 + r;
        #pragma unroll
        for (int t = 0; t < 4; t++) {
          const int row = rowb + t;
          const long idx = (long)row * ldc + col;
          float v = acc[i][j][t];
          if (EPI == EP_BIAS)          { v += bias[col]; }
          else if (EPI == EP_ADDRELUH) { v += (float)((const f16*)aux1)[(long)row * 256 + col];
                                         v = v > 0.f ? v : 0.f; }
          else if (EPI == EP_AGG)      { v = (v + aux1[idx]) * aux2[row]; }
          if (OUTM == OH) ((f16*)Cb)[idx] = (f16)v;
          else            ((float*)Cb)[idx] = v;
          if (EPI == EP_AGG && Cs) {
            short hh = f2bf(v);
            Cs[idx] = hh;
            Cs[csLo + idx] = f2bf(v - bf2f(hh));
          }
        }
      }
    }
  }
}

// ----- split-bf16 gate GEMM, tile 128x128, BK=64, 8 waves, 16x16x32 MFMA -----
// GM_Z: K=768, q0=copy P1 (inv_s), q1=copy P2 (outv_s), q2=iv*ov from f32 A,A2.
// GM_UR: K=512, q0=copy P1 (cur_s), q1=copy P2 (nv_s).
// GM_M: K=512, q0=r*cur from f32 A(lda),A2, q1=copy P2 (nv_s).
// Copies read pre-split bf16 planes (hi at P, lo at P+pLo).
template<int AMODE, int EPI>
__global__ __launch_bounds__(512) void ggemm(
    const float* __restrict__ A, const float* __restrict__ A2,
    const short* __restrict__ P1, const short* __restrict__ P2, long pLo,
    const short* __restrict__ Bw, float* __restrict__ C,
    short* __restrict__ Cs, long csLo,
    const float* __restrict__ aux1, const float* __restrict__ aux2, const float* __restrict__ bias,
    int Nd, int K, int lda, int ldb, int ldc, long bLo)
{
  int bxi, byi, bzu;
  xcd_remap(bxi, byi, bzu);
  const int m0 = byi * 128;
  const int n0 = bxi * 128;
  constexpr int HLA = 128 * 64;
  constexpr int HLB = 128 * 64;
  __shared__ short As[128 * 64 * 2];
  __shared__ short Bs[128 * 64 * 2];

  const int tid = threadIdx.x;
  const int wid = tid >> 6, lane = tid & 63;
  const int wm = (wid >> 1) * 32, wn = (wid & 1) * 64;
  const int r = lane & 15, g = lane >> 4;

  f32x4 acc[2][4];
  #pragma unroll
  for (int i = 0; i < 2; i++)
    #pragma unroll
    for (int j = 0; j < 4; j++) acc[i][j] = (f32x4){0.f, 0.f, 0.f, 0.f};

  s16x8 rh0, rh1, rlo0, rlo1;       // staged A (16 bf16 hi + lo)
  s16x8 rbh0, rbh1, rbl0, rbl1;     // staged B

  auto loadA = [&](int k0) {
    const int row = tid >> 2, kc = (tid & 3) * 16;
    const int q = k0 >> 8, kd = (k0 + kc) & 255;
    const long base = (long)(m0 + row) * 256 + kd;
    bool copy; const short* P;
    if (AMODE == GM_Z)       { copy = (q < 2); P = (q == 0) ? P1 : P2; }
    else if (AMODE == GM_UR) { copy = true;    P = (q == 0) ? P1 : P2; }
    else                     { copy = (q == 1); P = P2; }   // GM_M
    if (copy) {
      rh0  = *(const s16x8*)&P[base];
      rh1  = *(const s16x8*)&P[base + 8];
      rlo0 = *(const s16x8*)&P[pLo + base];
      rlo1 = *(const s16x8*)&P[pLo + base + 8];
    } else {
      float x[16];
      if (AMODE == GM_Z) {          // q==2: iv*ov
        #pragma unroll
        for (int u = 0; u < 4; u++) {
          f32x4 a = *(const f32x4*)(A  + base + 4 * u);
          f32x4 b = *(const f32x4*)(A2 + base + 4 * u);
          f32x4 v = a * b;
          x[4*u] = v.x; x[4*u+1] = v.y; x[4*u+2] = v.z; x[4*u+3] = v.w;
        }
      } else {                      // GM_M q==0: r*cur (A pitch lda)
        const long baseA = (long)(m0 + row) * lda + kd;
        #pragma unroll
        for (int u = 0; u < 4; u++) {
          f32x4 a = *(const f32x4*)(A  + baseA + 4 * u);
          f32x4 b = *(const f32x4*)(A2 + base + 4 * u);
          f32x4 v = a * b;
          x[4*u] = v.x; x[4*u+1] = v.y; x[4*u+2] = v.z; x[4*u+3] = v.w;
        }
      }
      short hh[16], ll[16];
      #pragma unroll
      for (int e = 0; e < 16; e++) { hh[e] = f2bf(x[e]); ll[e] = f2bf(x[e] - bf2f(hh[e])); }
      rh0  = (s16x8){hh[0],hh[1],hh[2],hh[3],hh[4],hh[5],hh[6],hh[7]};
      rh1  = (s16x8){hh[8],hh[9],hh[10],hh[11],hh[12],hh[13],hh[14],hh[15]};
      rlo0 = (s16x8){ll[0],ll[1],ll[2],ll[3],ll[4],ll[5],ll[6],ll[7]};
      rlo1 = (s16x8){ll[8],ll[9],ll[10],ll[11],ll[12],ll[13],ll[14],ll[15]};
    }
  };
  auto storeA = [&]() {
    const int row = tid >> 2, kc = (tid & 3) * 16;
    const int i0 = swz(row, row * 64 + kc), i1 = swz(row, row * 64 + kc + 8);
    *(s16x8*)&As[i0] = rh0;
    *(s16x8*)&As[i1] = rh1;
    *(s16x8*)&As[HLA + i0] = rlo0;
    *(s16x8*)&As[HLA + i1] = rlo1;
  };
  auto loadB = [&](int k0) {
    const int row = tid >> 2, kc = (tid & 3) * 16;
    const long off = (long)(n0 + row) * ldb + k0 + kc;
    rbh0 = *(const s16x8*)&Bw[off];
    rbh1 = *(const s16x8*)&Bw[off + 8];
    rbl0 = *(const s16x8*)&Bw[bLo + off];
    rbl1 = *(const s16x8*)&Bw[bLo + off + 8];
  };
  auto storeB = [&]() {
    const int row = tid >> 2, kc = (tid & 3) * 16;
    const int i0 = swz(row, row * 64 + kc), i1 = swz(row, row * 64 + kc + 8);
    *(s16x8*)&Bs[i0] = rbh0;
    *(s16x8*)&Bs[i1] = rbh1;
    *(s16x8*)&Bs[HLB + i0] = rbl0;
    *(s16x8*)&Bs[HLB + i1] = rbl1;
  };

  loadA(0); loadB(0);
  storeA(); storeB();
  __syncthreads();

  const int NT = K >> 6;
  for (int t = 0; t < NT; t++) {
    const bool more = (t + 1 < NT);
    if (more) { loadA((t + 1) << 6); loadB((t + 1) << 6); }
    #pragma unroll
    for (int ks = 0; ks < 2; ks++) {
      s16x8 ah[2], al[2], bh[4], bl[4];
      #pragma unroll
      for (int i = 0; i < 2; i++) {
        const int rw = wm + i * 16 + r;
        const int ix = swz(rw, rw * 64 + ks * 32 + g * 8);
        ah[i] = *(const s16x8*)&As[ix];
        al[i] = *(const s16x8*)&As[HLA + ix];
      }
      #pragma unroll
      for (int j = 0; j < 4; j++) {
        const int rw = wn + j * 16 + r;
        const int ix = swz(rw, rw * 64 + ks * 32 + g * 8);
        bh[j] = *(const s16x8*)&Bs[ix];
        bl[j] = *(const s16x8*)&Bs[HLB + ix];
      }
      #pragma unroll
      for (int i = 0; i < 2; i++)
        #pragma unroll
        for (int j = 0; j < 4; j++) {
          acc[i][j] = __builtin_amdgcn_mfma_f32_16x16x32_bf16(ah[i], bh[j], acc[i][j], 0, 0, 0);
          acc[i][j] = __builtin_amdgcn_mfma_f32_16x16x32_bf16(ah[i], bl[j], acc[i][j], 0, 0, 0);
          acc[i][j] = __builtin_amdgcn_mfma_f32_16x16x32_bf16(al[i], bh[j], acc[i][j], 0, 0, 0);
        }
    }
    __syncthreads();
    if (more) { storeA(); storeB(); __syncthreads(); }
  }

  #pragma unroll
  for (int i = 0; i < 2; i++) {
    #pragma unroll
    for (int j = 0; j < 4; j++) {
      #pragma unroll
      for (int t = 0; t < 4; t++) {
        const int row = m0 + wm + i * 16 + g * 4 + t;
        const int col = n0 + wn + j * 16 + r;
        const long idx = (long)row * ldc + col;
        float v = acc[i][j][t];
        if (EPI == SE_GATE) {
          v += bias[col];
          float z = 1.f / (1.f + __expf(-v));
          const long ix = (long)row * 256 + col;
          v = (1.f - z) * aux1[ix] + z * aux2[ix];
        } else if (EPI == SE_SIG) {
          v = 1.f / (1.f + __expf(-v));
        } else { // SE_TANH
          v = tanhf(v);
        }
        C[idx] = v;
        if (EPI == SE_GATE && Cs) {
          short hh = f2bf(v);
          Cs[idx] = hh;
          Cs[csLo + idx] = f2bf(v - bf2f(hh));
        }
      }
    }
  }
}

// ---------------- small kernels ----------------

// combined z-gate weights: Wc[o][0:256]=W1+W4, [256:512]=W2-W4, [512:768]=W3; split-bf16
__global__ void combine_wz(const float* __restrict__ Wz, short* __restrict__ Wc, long loOff) {
  const int idx = blockIdx.x * 256 + threadIdx.x;   // over 256*768
  const int o = idx / 768, k = idx % 768;
  float v;
  if (k < 256)      v = Wz[o * 1024 + k] + Wz[o * 1024 + 768 + k];
  else if (k < 512) v = Wz[o * 1024 + 256 + (k - 256)] - Wz[o * 1024 + 768 + (k - 256)];
  else              v = Wz[o * 1024 + 512 + (k - 512)];
  short h = f2bf(v);
  Wc[idx] = h;
  Wc[loOff + idx] = f2bf(v - bf2f(h));
}

// Fused adjacency conversion: fp32 [R][C] -> f16 row-major + f16 transposed, plus
// per-n norm partials. SUMDST=false: row sums (e2n). SUMDST=true: column sums (n2e).
template<bool SUMDST>
__global__ void cvt_dual(const float* __restrict__ in, f16* __restrict__ outR,
                         f16* __restrict__ outT, float* __restrict__ part, int R, int C) {
  __shared__ f16 t[64][72];
  __shared__ float sacc[64][4];
  const long boff = (long)blockIdx.z * (long)R * C;
  const int r0 = blockIdx.x * 64, c0 = blockIdx.y * 64;
  const int tid = threadIdx.x;
  const int rl = tid >> 2, cl = (tid & 3) * 16;
  const float* src = in + boff + (long)(r0 + rl) * C + c0 + cl;
  f16 loc[16];
  float s = 0.f;
  #pragma unroll
  for (int u = 0; u < 4; u++) {
    f32x4 v = *(const f32x4*)(src + 4 * u);
    loc[4*u+0] = (f16)v.x; loc[4*u+1] = (f16)v.y; loc[4*u+2] = (f16)v.z; loc[4*u+3] = (f16)v.w;
    if (!SUMDST) s += v.x + v.y + v.z + v.w;
  }
  f16* dR = outR + boff + (long)(r0 + rl) * C + c0 + cl;
  *(f16x8*)dR       = *(const f16x8*)&loc[0];
  *(f16x8*)(dR + 8) = *(const f16x8*)&loc[8];
  *(f16x8*)&t[rl][cl]     = *(const f16x8*)&loc[0];
  *(f16x8*)&t[rl][cl + 8] = *(const f16x8*)&loc[8];
  if (!SUMDST) sacc[rl][tid & 3] = s;
  __syncthreads();
  const int cl2 = tid >> 2, rl2 = (tid & 3) * 16;
  f16x8 o0, o1;
  #pragma unroll
  for (int v = 0; v < 8; v++) { o0[v] = t[rl2 + v][cl2]; o1[v] = t[rl2 + 8 + v][cl2]; }
  if (SUMDST) {
    float s2 = 0.f;
    #pragma unroll
    for (int v = 0; v < 8; v++) s2 += (float)o0[v] + (float)o1[v];
    sacc[cl2][tid & 3] = s2;
  }
  f16* dT = outT + boff + (long)(c0 + cl2) * R + r0 + rl2;
  *(f16x8*)dT = o0;
  *(f16x8*)(dT + 8) = o1;
  __syncthreads();
  if (tid < 64) {
    float tot = sacc[tid][0] + sacc[tid][1] + sacc[tid][2] + sacc[tid][3];
    const int slot = SUMDST ? blockIdx.x : blockIdx.y;
    const int n    = (SUMDST ? c0 : r0) + tid;
    part[((long)blockIdx.z * 64 + slot) * Nn + n] = tot;
  }
}

__global__ void colfin64(const float* __restrict__ part, float* __restrict__ rn) {
  const int i = blockIdx.x * 256 + threadIdx.x;   // over B*N
  const int b = i >> 11, n = i & 2047;
  float s = 0.f;
  for (int c = 0; c < 64; c++) s += part[((long)b * 64 + c) * Nn + n];
  rn[i] = 1.f / (1.f + s);
}

// fallback-mode norm kernels (read fp32 adjacency)
__global__ void rowsum_kernel(const float* __restrict__ e2n, float* __restrict__ out) {
  const int gw = blockIdx.x * 4 + (threadIdx.x >> 6);
  const int lane = threadIdx.x & 63;
  const float* p = e2n + (long)gw * Ee;
  float s = 0.f;
  for (int e = lane; e < Ee; e += 64) s += p[e];
  #pragma unroll
  for (int off = 32; off; off >>= 1) s += __shfl_down(s, off);
  if (lane == 0) out[gw] = 1.f / (1.f + s);
}
__global__ void colsum_kernel(const float* __restrict__ n2e, float* __restrict__ part) {
  const int n = blockIdx.x * 256 + threadIdx.x;
  const int c = blockIdx.y, b = blockIdx.z;
  const float* p = n2e + (long)b * Ee * Nn + (long)c * 256 * Nn + n;
  float s = 0.f;
  for (int e = 0; e < 256; e++) s += p[(long)e * Nn];
  part[((long)b * 16 + c) * Nn + n] = s;
}
__global__ void colfin16(const float* __restrict__ part, float* __restrict__ rni) {
  const int i = blockIdx.x * 256 + threadIdx.x;
  const int b = i >> 11, n = i & 2047;
  float s = 0.f;
  #pragma unroll
  for (int c = 0; c < 16; c++) s += part[((long)b * 16 + c) * Nn + n];
  rni[i] = 1.f / (1.f + s);
}

__global__ void cvt_half(const float* __restrict__ src, f16* __restrict__ dst) {
  const long i4 = (long)blockIdx.x * 256 + threadIdx.x;
  f32x4 v = *(const f32x4*)&src[i4 * 4];
  *(f16x4*)&dst[i4 * 4] = (f16x4){(f16)v.x, (f16)v.y, (f16)v.z, (f16)v.w};
}

__global__ void cvt_half_split(const float* __restrict__ src, f16* __restrict__ dst, long loOff) {
  const long i4 = (long)blockIdx.x * 256 + threadIdx.x;
  f32x4 v = *(const f32x4*)&src[i4 * 4];
  f16x4 h = {(f16)v.x, (f16)v.y, (f16)v.z, (f16)v.w};
  *(f16x4*)&dst[i4 * 4] = h;
  f16x4 l = {(f16)(v.x - (float)h[0]), (f16)(v.y - (float)h[1]),
             (f16)(v.z - (float)h[2]), (f16)(v.w - (float)h[3])};
  *(f16x4*)&dst[loOff + i4 * 4] = l;
}

// fp32 -> split-bf16 (hi plane at dst, lo at dst+loOff)
__global__ void cvt_bf_split(const float* __restrict__ src, short* __restrict__ dst, long loOff) {
  const long i4 = (long)blockIdx.x * 256 + threadIdx.x;
  f32x4 v = *(const f32x4*)&src[i4 * 4];
  s16x4 h = { f2bf(v.x), f2bf(v.y), f2bf(v.z), f2bf(v.w) };
  *(s16x4*)&dst[i4 * 4] = h;
  s16x4 l = { f2bf(v.x - bf2f(h.x)), f2bf(v.y - bf2f(h.y)),
              f2bf(v.z - bf2f(h.z)), f2bf(v.w - bf2f(h.w)) };
  *(s16x4*)&dst[loOff + i4 * 4] = l;
}

__global__ void init_cur(const float* __restrict__ node_vec, float* __restrict__ cur,
                         f16* __restrict__ cur_h, long loOff,
                         short* __restrict__ cur_s, long sLo) {
  const long i4 = (long)blockIdx.x * 256 + threadIdx.x;
  f32x4 v = *(const f32x4*)&node_vec[i4 * 4];
  *(f32x4*)&cur[i4 * 4] = v;
  f16x4 h = {(f16)v.x, (f16)v.y, (f16)v.z, (f16)v.w};
  *(f16x4*)&cur_h[i4 * 4] = h;
  f16x4 l = {(f16)(v.x - (float)h[0]), (f16)(v.y - (float)h[1]),
             (f16)(v.z - (float)h[2]), (f16)(v.w - (float)h[3])};
  *(f16x4*)&cur_h[loOff + i4 * 4] = l;
  s16x4 bh = { f2bf(v.x), f2bf(v.y), f2bf(v.z), f2bf(v.w) };
  *(s16x4*)&cur_s[i4 * 4] = bh;
  s16x4 bl = { f2bf(v.x - bf2f(bh.x)), f2bf(v.y - bf2f(bh.y)),
               f2bf(v.z - bf2f(bh.z)), f2bf(v.w - bf2f(bh.w)) };
  *(s16x4*)&cur_s[sLo + i4 * 4] = bl;
}

// cur [B*N,256] f32 -> cur_hT hi/lo planes [B][256][2048] halves
__global__ void transposeT(const float* __restrict__ cur, f16* __restrict__ curT, long loOff) {
  __shared__ f16 th[64][72];
  __shared__ f16 tl[64][72];
  const int b = blockIdx.z, nt = blockIdx.x * 64, dt = blockIdx.y * 64;
  const int tid = threadIdx.x;
  const int nl = tid >> 2, d0 = (tid & 3) * 16;
  const float* src = cur + ((long)b * Nn + nt + nl) * 256 + dt + d0;
  #pragma unroll
  for (int u = 0; u < 4; u++) {
    f32x4 v = *(const f32x4*)(src + 4 * u);
    f16x4 h = {(f16)v.x, (f16)v.y, (f16)v.z, (f16)v.w};
    *(f16x4*)&th[nl][d0 + 4 * u] = h;
    f16x4 l = {(f16)(v.x - (float)h[0]), (f16)(v.y - (float)h[1]),
               (f16)(v.z - (float)h[2]), (f16)(v.w - (float)h[3])};
    *(f16x4*)&tl[nl][d0 + 4 * u] = l;
  }
  __syncthreads();
  const int dl = tid >> 2, n0l = (tid & 3) * 16;
  f16x8 o0, o1, p0, p1;
  #pragma unroll
  for (int v = 0; v < 8; v++) {
    o0[v] = th[n0l + v][dl];     o1[v] = th[n0l + 8 + v][dl];
    p0[v] = tl[n0l + v][dl];     p1[v] = tl[n0l + 8 + v][dl];
  }
  f16* dst = curT + (long)b * (256 * Nn) + (long)(dt + dl) * Nn + nt + n0l;
  *(f16x8*)dst = o0;
  *(f16x8*)(dst + 8) = o1;
  *(f16x8*)(dst + loOff) = p0;
  *(f16x8*)(dst + loOff + 8) = p1;
}

__global__ void gruf_kernel(const float* __restrict__ urb, const float* __restrict__ m,
                            float* __restrict__ cur, f16* __restrict__ cur_h, long loOff,
                            short* __restrict__ cur_s, long sLo) {
  const long i = (long)blockIdx.x * 256 + threadIdx.x;
  const long bn = i >> 8; const int d = i & 255;
  const float uu = urb[bn * 512 + d];
  const float v = (1.f - uu) * cur[i] + uu * m[i];
  cur[i] = v;
  f16 h = (f16)v;
  cur_h[i] = h;
  cur_h[loOff + i] = (f16)(v - (float)h);
  short bh = f2bf(v);
  cur_s[i] = bh;
  cur_s[sLo + i] = f2bf(v - bf2f(bh));
}

__global__ void maxpool1(const float* __restrict__ pooled, float* __restrict__ part) {
  const int d = threadIdx.x, c = blockIdx.x, b = blockIdx.y;
  const float* p = pooled + ((long)b * Nn + c * 256) * Dd + d;
  float m = -INFINITY;
  for (int n = 0; n < 256; n++) m = fmaxf(m, p[(long)n * Dd]);
  part[(b * 8 + c) * Dd + d] = m;
}
__global__ void maxpool2(const float* __restrict__ part, float* __restrict__ out1) {
  const int d = threadIdx.x, b = blockIdx.x;
  float m = -INFINITY;
  #pragma unroll
  for (int c = 0; c < 8; c++) m = fmaxf(m, part[(b * 8 + c) * Dd + d]);
  out1[b * Dd + d] = m;
}
__global__ void transpose_out(const float* __restrict__ cur, float* __restrict__ out0) {
  const long i = (long)blockIdx.x * 256 + threadIdx.x;
  const int d = i & 255;
  const long nb = i >> 8;
  const int b = nb & 7;
  const long n = nb >> 3;
  out0[i] = cur[((long)b * Nn + n) * Dd + d];
}

extern "C" void kernel_launch(void* const* d_in, const int* in_sizes, int n_in,
                              void* d_out, int out_size, void* d_ws, size_t ws_size,
                              hipStream_t stream) {
  const float* node_vec = (const float*)d_in[0];
  const float* edge_vec = (const float*)d_in[1];
  const float* n2e      = (const float*)d_in[2];   // [B,E,N]
  const float* e2n      = (const float*)d_in[3];   // [B,N,E]
  const float* W_fuse   = (const float*)d_in[5];   // [256,512]
  const float* b_fuse   = (const float*)d_in[6];
  const float* W_z      = (const float*)d_in[7];   // [256,1024]
  const float* b_z      = (const float*)d_in[8];
  const float* W_u      = (const float*)d_in[9];
  const float* W_r      = (const float*)d_in[10];
  const float* W_m      = (const float*)d_in[11];
  const float* W_max    = (const float*)d_in[12];  // [256,256]

  const long ND  = (long)Bb * Nn * Dd;   // 4194304
  const long EDb = (long)Ee * Dd;        // 1048576
  const long NDb = (long)Nn * Dd;        // 524288
  const long ED  = (long)Bb * EDb;       // 8388608
  const long ADJb = (long)Ee * Nn;       // 8388608 (per batch)
  const long ADJ = (long)Bb * ADJb;      // 67108864
  const int  BN  = Bb * Nn;

  // ---- arena ----
  char* p = (char*)d_ws;
  auto alloc = [&](size_t bytes) { char* r = p; p += (bytes + 255) & ~(size_t)255; return r; };

  const size_t need_full =
      (size_t)4 * ADJ * 2
      + (size_t)ED * 2                        // ev_h
      + (size_t)4 * ED * 2                    // E1h2, E2T2
      + (size_t)ED * 2                        // EVWh (f16)
      + (size_t)4 * ND * 2                    // cur_h, cur_hT
      + (size_t)(2 * 131072 + 2 * 65536) * 2
      + (size_t)(2 * 262144 + 2 * 262144 + 2 * 131072) * 2
      + (size_t)2 * 196608 * 2                // Wzc_s
      + (size_t)5 * ND * 4
      + (size_t)BN * 512 * 4
      + (size_t)(2 * BN + 2 * 64 * BN) * 4
      + (size_t)(4 * ND + 2 * ND + 2 * ND) * 2  // outinv_s, nv_s, cur_s
      + 64 * 1024;
  const bool full = ws_size >= need_full;

  f16 *adjEO = nullptr, *adjAG = nullptr;
  f16 *n2e_h = nullptr, *e2n_hT = nullptr, *e2n_h = nullptr, *n2e_hT = nullptr;
  if (full) {
    adjEO = (f16*)alloc((size_t)2 * ADJ * 2);
    adjAG = (f16*)alloc((size_t)2 * ADJ * 2);
    n2e_h = adjEO;  e2n_hT = adjEO + ADJ;
    e2n_h = adjAG;  n2e_hT = adjAG + ADJ;
  }
  f16* ev_h    = (f16*)alloc(ED * 2);
  f16* E1h2    = (f16*)alloc((size_t)2 * ED * 2);  // 16 slabs [Ee][256]
  f16* E2T2    = (f16*)alloc((size_t)2 * ED * 2);  // 16 slabs [256][Ee]
  f16* EVWh    = (f16*)alloc(ED * 2);              // 8 slabs [Ee][256] f16
  f16* cur_h   = (f16*)alloc(2 * ND * 2);
  f16* cur_hT  = (f16*)alloc(2 * ND * 2);
  f16* Wf_h    = (f16*)alloc(2 * 131072 * 2);
  f16* Wmax_h  = (f16*)alloc(2 * 65536 * 2);
  short* Wz_s  = (short*)alloc((size_t)2 * 262144 * 2);   // (unused in full path; kept for safety)
  short* Wur_s = (short*)alloc((size_t)2 * 262144 * 2);
  short* Wm_s  = (short*)alloc((size_t)2 * 131072 * 2);
  short* Wzc_s = (short*)alloc((size_t)2 * 196608 * 2);   // combined z weights [256][768] hi+lo
  float* cur   = (float*)alloc(ND * 4);
  float* outv  = (float*)alloc(2 * ND * 4);        // outv|inv contiguous
  float* inv   = outv + ND;
  float* nv    = (float*)alloc(ND * 4);
  float* urb   = (float*)alloc((size_t)BN * 512 * 4);
  float* mb    = (float*)alloc(ND * 4);
  float* rno   = (float*)alloc(2 * BN * 4);        // rno|rni contiguous
  float* rni   = rno + BN;
  float* rnopart = (float*)alloc((size_t)64 * BN * 4);
  float* rnipart = (float*)alloc((size_t)64 * BN * 4);
  float* maxpart = (float*)alloc(BN * 4);
  short* outinv_s = (short*)alloc((size_t)4 * ND * 2);  // hi [2ND] + lo [2ND]
  short* nv_s     = (short*)alloc((size_t)2 * ND * 2);  // hi [ND] + lo [ND]
  short* cur_s    = (short*)alloc((size_t)2 * ND * 2);  // hi [ND] + lo [ND]
  short* outv_s   = outinv_s;
  short* inv_s    = outinv_s + ND;

  float* out0 = (float*)d_out;
  float* out1 = out0 + ND;

  // ---- one-time conversions + norms + transposed adjacency caches ----
  if (full) {
    cvt_dual<false><<<dim3(Nn / 64, Ee / 64, Bb), 256, 0, stream>>>(
        e2n, e2n_h, e2n_hT, rnopart, Nn, Ee);
    cvt_dual<true><<<dim3(Ee / 64, Nn / 64, Bb), 256, 0, stream>>>(
        n2e, n2e_h, n2e_hT, rnipart, Ee, Nn);
    colfin64<<<BN / 256, 256, 0, stream>>>(rnopart, rno);
    colfin64<<<BN / 256, 256, 0, stream>>>(rnipart, rni);
  } else {
    colsum_kernel<<<dim3(Nn / 256, 16, Bb), 256, 0, stream>>>(n2e, rnipart);
    colfin16<<<BN / 256, 256, 0, stream>>>(rnipart, rni);
    rowsum_kernel<<<BN / 4, 256, 0, stream>>>(e2n, rno);
  }
  cvt_half<<<(int)(ED / 1024), 256, 0, stream>>>(edge_vec, ev_h);
  cvt_half_split<<<131072 / 1024, 256, 0, stream>>>(W_fuse, Wf_h, 131072);
  cvt_half_split<<<65536 / 1024, 256, 0, stream>>>(W_max, Wmax_h, 65536);
  combine_wz<<<196608 / 256, 256, 0, stream>>>(W_z, Wzc_s, 196608);
  cvt_bf_split<<<131072 / 1024, 256, 0, stream>>>(W_u, Wur_s, 262144);
  cvt_bf_split<<<131072 / 1024, 256, 0, stream>>>(W_r, Wur_s + 131072, 262144);
  cvt_bf_split<<<131072 / 1024, 256, 0, stream>>>(W_m, Wm_s, 131072);
  init_cur<<<(int)(ND / 1024), 256, 0, stream>>>(node_vec, cur, cur_h, ND, cur_s, ND);
  transposeT<<<dim3(Nn / 64, 4, Bb), 256, 0, stream>>>(cur, cur_hT, ND);

  // EVWh = ev @ Wf[:,256:]^T + b_fuse  (hop-invariant, K=256, split-B) -> f16
  hgemm<HN, true, 1, EP_BIAS, OH><<<dim3(2, Ee / 128, Bb), 512, 0, stream>>>(
      ev_h, Wf_h + 256, EVWh, nullptr, nullptr, b_fuse,
      Ee, 256, 256, 256, 512, 256, EDb, 0, EDb, 0, 0, 0, 131072, 0, 0, nullptr, 0);

  for (int h = 0; h < HOPS; h++) {
    if (full) {
      // EO1|EI1 = (n2e_h | e2n_hT) @ cur -> E1h2 ; B=cur_hT split, wraps@8
      hgemm<HN, true, 1, EP_NONE, OH><<<dim3(2, Ee / 128, 2 * Bb), 512, 0, stream>>>(
          adjEO, cur_hT, E1h2, nullptr, nullptr, nullptr,
          Ee, 256, Nn, Nn, Nn, 256, ADJb, NDb, EDb, 0, 0, 0, ND, 7, 0, nullptr, 0);
      // EO2|EI2 = relu(E1 @ Wf1^T + EVWh) -> E2T2 (f16-T); sAux1 in f32 units = EDb/2
      hgemm<HN, true, 1, EP_ADDRELUH, OHT><<<dim3(2, Ee / 128, 2 * Bb), 512, 0, stream>>>(
          E1h2, Wf_h, E2T2, (const float*)EVWh, nullptr, nullptr,
          Ee, 256, 256, 256, 512, Ee, EDb, 0, EDb, EDb / 2, 0, 0, 131072, 0, 7, nullptr, 0);
      // out|in = ((e2n_h | n2e_hT) @ E2 + cur) * (rno|rni) -> outv|inv (+ split-bf16 planes)
      hgemm<HN, true, 0, EP_AGG, OF><<<dim3(2, Nn / 128, 2 * Bb), 512, 0, stream>>>(
          adjAG, E2T2, outv, cur, rno, nullptr,
          Nn, 256, Ee, Ee, Ee, 256, ADJb, EDb, NDb, NDb, (long)Nn, 0, 0, 15, 7,
          outinv_s, 2 * ND);
    } else {
      hgemm<HN, false, 1, EP_NONE, OH><<<dim3(2, Ee / 128, Bb), 512, 0, stream>>>(
          n2e, cur_hT, E1h2, nullptr, nullptr, nullptr,
          Ee, 256, Nn, Nn, Nn, 256, ADJb, NDb, EDb, 0, 0, 0, ND, 7, 0, nullptr, 0);
      hgemm<HT, false, 1, EP_NONE, OH><<<dim3(2, Ee / 128, Bb), 512, 0, stream>>>(
          e2n, cur_hT, E1h2 + ED, nullptr, nullptr, nullptr,
          Ee, 256, Nn, Ee, Nn, 256, ADJb, NDb, EDb, 0, 0, 0, ND, 7, 0, nullptr, 0);
      hgemm<HN, true, 1, EP_ADDRELUH, OHT><<<dim3(2, Ee / 128, 2 * Bb), 512, 0, stream>>>(
          E1h2, Wf_h, E2T2, (const float*)EVWh, nullptr, nullptr,
          Ee, 256, 256, 256, 512, Ee, EDb, 0, EDb, EDb / 2, 0, 0, 131072, 0, 7, nullptr, 0);
      hgemm<HN, false, 0, EP_AGG, OF><<<dim3(2, Nn / 128, Bb), 512, 0, stream>>>(
          e2n, E2T2, outv, cur, rno, nullptr,
          Nn, 256, Ee, Ee, Ee, 256, (long)Nn * Ee, EDb, NDb, NDb, (long)Nn, 0, 0, 15, 7,
          outinv_s, 2 * ND);
      hgemm<HT, false, 0, EP_AGG, OF><<<dim3(2, Nn / 128, Bb), 512, 0, stream>>>(
          n2e, E2T2 + ED, inv, cur, rni, nullptr,
          Nn, 256, Ee, Nn, Ee, 256, (long)Ee * Nn, EDb, NDb, NDb, (long)Nn, 0, 0, 15, 7,
          outinv_s + ND, 2 * ND);
    }
    // gated fusion: nv = (1-z)*inv + z*outv  [split-bf16, combined weights K=768]
    ggemm<GM_Z, SE_GATE><<<dim3(2, BN / 128, 1), 512, 0, stream>>>(
        inv, outv, inv_s, outv_s, 2 * ND, Wzc_s, nv, nv_s, ND,
        inv, outv, b_z, 256, 768, 256, 768, 256, 196608);
    // u|r = sigmoid(concat(cur,nv) @ [W_u;W_r]^T) -> urb [BN,512]  (pure-copy A)
    ggemm<GM_UR, SE_SIG><<<dim3(4, BN / 128, 1), 512, 0, stream>>>(
        nullptr, nullptr, cur_s, nv_s, ND, Wur_s, urb, nullptr, 0,
        nullptr, nullptr, nullptr, 512, 512, 0, 512, 512, 262144);
    // m = tanh(concat(r*cur, nv) @ W_m^T) -> mb
    ggemm<GM_M, SE_TANH><<<dim3(2, BN / 128, 1), 512, 0, stream>>>(
        urb + 256, cur, nullptr, nv_s, ND, Wm_s, mb, nullptr, 0,
        nullptr, nullptr, nullptr, 256, 512, 512, 512, 256, 131072);
    // cur = (1-u)*cur + u*m  (+ split halves, f16 and bf16)
    gruf_kernel<<<(int)(ND / 256), 256, 0, stream>>>(urb, mb, cur, cur_h, ND, cur_s, ND);
    if (h < HOPS - 1)
      transposeT<<<dim3(Nn / 64, 4, Bb), 256, 0, stream>>>(cur, cur_hT, ND);
  }

  // pooled = cur @ W_max^T -> urb (f32); both operands split
  hgemm<HN, true, 3, EP_NONE, OF><<<dim3(2, BN / 128, 1), 512, 0, stream>>>(
      cur_h, Wmax_h, urb, nullptr, nullptr, nullptr,
      BN, 256, 256, 256, 256, 256, 0, 0, 0, 0, 0, ND, 65536, 0, 0, nullptr, 0);
  maxpool1<<<dim3(8, Bb), 256, 0, stream>>>(urb, maxpart);
  maxpool2<<<Bb, 256, 0, stream>>>(maxpart, out1);

  transpose_out<<<(int)(ND / 256), 256, 0, stream>>>(cur, out0);
}